// Round 4
// baseline (599.287 us; speedup 1.0000x reference)
//
#include <hip/hip_runtime.h>
#include <hip/hip_bf16.h>
#include <math.h>

// Problem sizes (fixed)
#define NROW    4096
#define DPROJ   1024
#define LDHB    1408         // 1024 + 256 + 64 + pad
#define HEAD_V  20003
#define TAIL_V  10000
#define HEAD_VP 20224        // 79*256
#define TAIL1_P 10240        // 40*256
#define TAIL_VP 10112        // 79*128 (tails 2,3 on 128-tile kernel)
#define NBH     79           // head col-blocks (256 wide)
#define NBT1    40           // tail1 col-blocks (256 wide)
#define NBT     79           // tail2/3 col-blocks (128 wide)

typedef short short8 __attribute__((ext_vector_type(8)));
typedef float f32x4  __attribute__((ext_vector_type(4)));

__device__ __forceinline__ ushort f2bf(float f) {           // RNE f32 -> bf16
    unsigned u = __builtin_bit_cast(unsigned, f);
    return (ushort)((u + 0x7FFFu + ((u >> 16) & 1u)) >> 16);
}
__device__ __forceinline__ float bf2f(ushort u) {
    unsigned x = (unsigned)u << 16;
    return __builtin_bit_cast(float, x);
}

#define GLOAD16(gp, lp) __builtin_amdgcn_global_load_lds(                     \
    (const __attribute__((address_space(1))) void*)(gp),                      \
    (__attribute__((address_space(3))) void*)(lp), 16, 0, 0)

// ---------------------------------------------------------------------------
// cast hidden f32 -> bf16  (4096x1024)
// ---------------------------------------------------------------------------
__global__ void cast_hidden_k(const float* __restrict__ h, ushort* __restrict__ hb) {
    int i = (blockIdx.x * 256 + threadIdx.x) * 4;
    float4 v = *(const float4*)(h + i);
    ushort4 o = {f2bf(v.x), f2bf(v.y), f2bf(v.z), f2bf(v.w)};
    *(ushort4*)(hb + i) = o;
}

// ---------------------------------------------------------------------------
// transpose-cast proj concat -> pbT [1408][1024] bf16 (row = out col, K-contig)
// ---------------------------------------------------------------------------
__global__ void cast_transpose_proj(const float* __restrict__ p0, const float* __restrict__ p1,
                                    const float* __restrict__ p2, const float* __restrict__ p3,
                                    ushort* __restrict__ pbT) {
    __shared__ float tile[64][65];
    const int t  = threadIdx.x;
    const int kb = blockIdx.x * 64;
    const int cb = blockIdx.y * 64;
    for (int p = 0; p < 4; ++p) {
        int kl = p * 16 + (t >> 4);
        int c4 = (t & 15) * 4;
        int k  = kb + kl;
        for (int j = 0; j < 4; ++j) {
            int c = cb + c4 + j;
            float v = 0.f;
            if      (c < 1024) v = p0[(size_t)k * 1024 + c];
            else if (c < 1280) v = p1[(size_t)k * 256  + (c - 1024)];
            else if (c < 1344) v = p2[(size_t)k * 64   + (c - 1280)];
            else if (c < 1360) v = p3[(size_t)k * 16   + (c - 1344)];
            tile[kl][c4 + j] = v;
        }
    }
    __syncthreads();
    for (int p = 0; p < 4; ++p) {
        int cl = p * 16 + (t >> 4);
        int k4 = (t & 15) * 4;
        ushort4 o = {f2bf(tile[k4 + 0][cl]), f2bf(tile[k4 + 1][cl]),
                     f2bf(tile[k4 + 2][cl]), f2bf(tile[k4 + 3][cl])};
        *(ushort4*)(pbT + (size_t)(cb + cl) * 1024 + kb + k4) = o;
    }
}

// ---------------------------------------------------------------------------
// cast head weight: [w0 (20000) | cluster_w (3) | zeros] -> WH [20224][1024]
// ---------------------------------------------------------------------------
__global__ void cast_head_w(const float* __restrict__ w0, const float* __restrict__ cw,
                            ushort* __restrict__ dst) {
    const int row = blockIdx.x;
    const int c   = threadIdx.x * 4;
    float4 v = {0.f, 0.f, 0.f, 0.f};
    if (row < 20000)      v = *(const float4*)(w0 + (size_t)row * 1024 + c);
    else if (row < 20003) v = *(const float4*)(cw + (size_t)(row - 20000) * 1024 + c);
    ushort4 o = {f2bf(v.x), f2bf(v.y), f2bf(v.z), f2bf(v.w)};
    *(ushort4*)(dst + (size_t)row * 1024 + c) = o;
}

// ---------------------------------------------------------------------------
// cast tail weight with row pad + K pad: src [rows_real][kin] -> dst [rows_pad][KOUT]
// ---------------------------------------------------------------------------
template<int KOUT>
__global__ void cast_tail_w(const float* __restrict__ src, ushort* __restrict__ dst,
                            int rows_real, int kin, int rows_pad) {
    int idx = blockIdx.x * 256 + threadIdx.x;
    const int n = rows_pad * KOUT;
    if (idx >= n) return;
    int r = idx / KOUT, k = idx - r * KOUT;
    float v = (r < rows_real && k < kin) ? src[(size_t)r * kin + k] : 0.f;
    dst[idx] = f2bf(v);
}

// ---------------------------------------------------------------------------
// Proj GEMM: Hb[4096][1408] = hb @ pbT^T  (m97-style 128x128, unchanged)
// ---------------------------------------------------------------------------
__global__ __launch_bounds__(256) void proj_gemm_mfma(const ushort* __restrict__ A,
                                                      const ushort* __restrict__ B,
                                                      ushort* __restrict__ C) {
    __shared__ ushort As[128 * 32];
    __shared__ ushort Bs[128 * 32];
    const int t  = threadIdx.x;
    const int wv = t >> 6, l = t & 63, lr = l & 15, lh = l >> 4;
    const int wr = wv >> 1, wc = wv & 1;
    const int rb = blockIdx.x * 128, cb = blockIdx.y * 128;
    f32x4 acc[4][4] = {};
    for (int k0 = 0; k0 < DPROJ; k0 += 32) {
        __syncthreads();
        #pragma unroll
        for (int is = 0; is < 2; ++is) {
            int rr = (t >> 2) + is * 64;
            GLOAD16(A + (size_t)(rb + rr) * DPROJ + k0 + (t & 3) * 8,
                    (char*)As + wv * 1024 + is * 4096);
            GLOAD16(B + (size_t)(cb + rr) * DPROJ + k0 + (t & 3) * 8,
                    (char*)Bs + wv * 1024 + is * 4096);
        }
        __syncthreads();
        short8 af[4], bf[4];
        #pragma unroll
        for (int m = 0; m < 4; ++m)
            af[m] = *(const short8*)(As + (wr * 64 + m * 16 + lr) * 32 + lh * 8);
        #pragma unroll
        for (int n = 0; n < 4; ++n)
            bf[n] = *(const short8*)(Bs + (wc * 64 + n * 16 + lr) * 32 + lh * 8);
        #pragma unroll
        for (int m = 0; m < 4; ++m)
            #pragma unroll
            for (int n = 0; n < 4; ++n)
                acc[m][n] = __builtin_amdgcn_mfma_f32_16x16x32_bf16(af[m], bf[n], acc[m][n], 0, 0, 0);
    }
    #pragma unroll
    for (int m = 0; m < 4; ++m)
        #pragma unroll
        for (int n = 0; n < 4; ++n)
            #pragma unroll
            for (int r = 0; r < 4; ++r) {
                int rl = wr * 64 + m * 16 + lh * 4 + r;
                int cl = wc * 64 + n * 16 + lr;
                C[(size_t)(rb + rl) * LDHB + cb + cl] = f2bf(acc[m][n][r]);
            }
}

// ---------------------------------------------------------------------------
// 256x256-tile, BK=32, 512-thr GEMM + sum-exp. 3-deep LDS ring (96 KB dyn),
// T2 XOR-swizzle (elem ^= ((row>>3)&1)<<4), counted vmcnt(4) checkpoints,
// raw barriers + setprio around MFMA clusters, 2 phases x 16 MFMA per K-step.
// ---------------------------------------------------------------------------
template<int K>
__global__ __launch_bounds__(512, 2) void gemm_sumexp_256(
        const ushort* __restrict__ A, int lda,
        const ushort* __restrict__ B,
        const float* __restrict__ bias, const float* __restrict__ biasx,
        int splitB, int vocab,
        float* __restrict__ partial, int nCB, int gridM) {
    extern __shared__ ushort lds[];     // 3 bufs x (A 8192 + B 8192) ushorts
    const int t  = threadIdx.x;
    const int wv = t >> 6, l = t & 63, lr = l & 15, lh = l >> 4;
    const int wr = wv >> 2, wc = wv & 3;             // 2M x 4N waves
    // XCD-aware swizzle (grid % 8 == 0 by construction)
    const int cpx = gridDim.x >> 3;
    const int bid = blockIdx.x;
    const int swz = (bid & 7) * cpx + (bid >> 3);
    const int bm = swz % gridM, bn = swz / gridM;
    const int rb = bm * 256, cb = bn * 256;
    constexpr int NT = K / 32;

    const int srow = t >> 2;                         // 0..127
    const int scol = (t & 3) * 8;                    // element col chunk
    // stage: LDS dest is wave-linear; SOURCE col pre-inverse-swizzled (rule #21)
    auto stageA = [&](int kt, int buf) {
        const int k0 = kt * 32;
        #pragma unroll
        for (int j = 0; j < 2; ++j) {
            int row = j * 128 + srow;
            int csw = scol ^ (((row >> 3) & 1) << 4);
            GLOAD16(A + (size_t)(rb + row) * lda + k0 + csw,
                    (char*)lds + buf * 32768 + j * 8192 + wv * 1024);
        }
    };
    auto stageB = [&](int kt, int buf) {
        const int k0 = kt * 32;
        #pragma unroll
        for (int j = 0; j < 2; ++j) {
            int row = j * 128 + srow;
            int csw = scol ^ (((row >> 3) & 1) << 4);
            GLOAD16(B + (size_t)(cb + row) * K + k0 + csw,
                    (char*)lds + buf * 32768 + 16384 + j * 8192 + wv * 1024);
        }
    };
    auto ldA = [&](int buf, int m) -> short8 {       // swizzled ds_read
        int row = wr * 128 + m * 16 + lr;
        int cu  = (lh * 8) ^ (((row >> 3) & 1) << 4);
        return *(const short8*)(lds + buf * 16384 + row * 32 + cu);
    };
    auto ldB = [&](int buf, int n) -> short8 {
        int row = wc * 64 + n * 16 + lr;
        int cu  = (lh * 8) ^ (((row >> 3) & 1) << 4);
        return *(const short8*)(lds + buf * 16384 + 8192 + row * 32 + cu);
    };

    f32x4 acc[8][4] = {};
    // prologue: stage tiles 0,1; wait tile0 (tile1's 4 loads stay in flight)
    stageA(0, 0); stageB(0, 0);
    if (NT > 1) { stageA(1, 1); stageB(1, 1); }
    if (NT > 1) asm volatile("s_waitcnt vmcnt(4)" ::: "memory");
    else        asm volatile("s_waitcnt vmcnt(0)" ::: "memory");
    asm volatile("s_barrier" ::: "memory");

    for (int kt = 0; kt < NT; ++kt) {
        const int cur = kt % 3, nxt = (kt + 2) % 3;
        short8 af[8], bf[4];
        // ---- phase 1: reads + A-stage + 16 MFMA (n 0..1)
        #pragma unroll
        for (int m = 0; m < 8; ++m) af[m] = ldA(cur, m);
        bf[0] = ldB(cur, 0); bf[1] = ldB(cur, 1);
        if (kt + 2 < NT) stageA(kt + 2, nxt);
        asm volatile("s_barrier" ::: "memory");
        __builtin_amdgcn_s_setprio(1);
        #pragma unroll
        for (int m = 0; m < 8; ++m)
            #pragma unroll
            for (int n = 0; n < 2; ++n)
                acc[m][n] = __builtin_amdgcn_mfma_f32_16x16x32_bf16(af[m], bf[n], acc[m][n], 0, 0, 0);
        __builtin_amdgcn_s_setprio(0);
        asm volatile("s_barrier" ::: "memory");
        // ---- phase 2: reads + B-stage + 16 MFMA (n 2..3)
        bf[2] = ldB(cur, 2); bf[3] = ldB(cur, 3);
        if (kt + 2 < NT) stageB(kt + 2, nxt);
        asm volatile("s_barrier" ::: "memory");
        __builtin_amdgcn_s_setprio(1);
        #pragma unroll
        for (int m = 0; m < 8; ++m)
            #pragma unroll
            for (int n = 2; n < 4; ++n)
                acc[m][n] = __builtin_amdgcn_mfma_f32_16x16x32_bf16(af[m], bf[n], acc[m][n], 0, 0, 0);
        __builtin_amdgcn_s_setprio(0);
        // ---- checkpoint: tile kt+1 landed; kt+2's 4 loads stay in flight
        if (kt + 2 < NT) asm volatile("s_waitcnt vmcnt(4)" ::: "memory");
        else             asm volatile("s_waitcnt vmcnt(0)" ::: "memory");
        asm volatile("s_barrier" ::: "memory");
    }

    // epilogue: exp(logit+bias), reduce; staging LDS is dead -> reuse as red
    float* red = (float*)lds;                        // [4][256]
    #pragma unroll
    for (int m = 0; m < 8; ++m)
        #pragma unroll
        for (int q = 0; q < 4; ++q) {
            float s = 0.f;
            #pragma unroll
            for (int n = 0; n < 4; ++n) {
                int col = cb + wc * 64 + n * 16 + lr;
                if (col < vocab) {
                    float bv = (col < splitB) ? bias[col] : biasx[col - splitB];
                    s += expf(acc[m][n][q] + bv);
                }
            }
            #pragma unroll
            for (int off = 1; off < 16; off <<= 1) s += __shfl_xor(s, off);
            if (lr == 0) red[wc * 256 + wr * 128 + m * 16 + lh * 4 + q] = s;
        }
    __syncthreads();
    if (t < 256)
        partial[(size_t)(rb + t) * nCB + bn] =
            red[t] + red[256 + t] + red[512 + t] + red[768 + t];
}

// ---------------------------------------------------------------------------
// 128x128 m97-style GEMM + sum-exp (tails 2,3 only)
// ---------------------------------------------------------------------------
template<int K>
__global__ __launch_bounds__(256) void gemm_sumexp_bf(
        const ushort* __restrict__ A,
        const ushort* __restrict__ B,
        const float* __restrict__ bias,
        int vocab, float* __restrict__ partial, int nCB) {
    __shared__ ushort As[128 * 32];
    __shared__ ushort Bs[128 * 32];
    __shared__ float  red[2][128];
    const int t  = threadIdx.x;
    const int wv = t >> 6, l = t & 63, lr = l & 15, lh = l >> 4;
    const int wr = wv >> 1, wc = wv & 1;
    const int rb = blockIdx.x * 128, cb = blockIdx.y * 128;
    f32x4 acc[4][4] = {};
    for (int k0 = 0; k0 < K; k0 += 32) {
        __syncthreads();
        #pragma unroll
        for (int is = 0; is < 2; ++is) {
            int rr = (t >> 2) + is * 64;
            GLOAD16(A + (size_t)(rb + rr) * LDHB + k0 + (t & 3) * 8,
                    (char*)As + wv * 1024 + is * 4096);
            GLOAD16(B + (size_t)(cb + rr) * K + k0 + (t & 3) * 8,
                    (char*)Bs + wv * 1024 + is * 4096);
        }
        __syncthreads();
        short8 af[4], bf[4];
        #pragma unroll
        for (int m = 0; m < 4; ++m)
            af[m] = *(const short8*)(As + (wr * 64 + m * 16 + lr) * 32 + lh * 8);
        #pragma unroll
        for (int n = 0; n < 4; ++n)
            bf[n] = *(const short8*)(Bs + (wc * 64 + n * 16 + lr) * 32 + lh * 8);
        #pragma unroll
        for (int m = 0; m < 4; ++m)
            #pragma unroll
            for (int n = 0; n < 4; ++n)
                acc[m][n] = __builtin_amdgcn_mfma_f32_16x16x32_bf16(af[m], bf[n], acc[m][n], 0, 0, 0);
    }
    float rs[4][4];
    #pragma unroll
    for (int m = 0; m < 4; ++m)
        #pragma unroll
        for (int r = 0; r < 4; ++r) {
            float s = 0.f;
            #pragma unroll
            for (int n = 0; n < 4; ++n) {
                int col = cb + wc * 64 + n * 16 + lr;
                if (col < vocab) s += expf(acc[m][n][r] + bias[col]);
            }
            rs[m][r] = s;
        }
    #pragma unroll
    for (int m = 0; m < 4; ++m)
        #pragma unroll
        for (int r = 0; r < 4; ++r) {
            #pragma unroll
            for (int off = 1; off < 16; off <<= 1)
                rs[m][r] += __shfl_xor(rs[m][r], off);
            if (lr == 0) red[wc][wr * 64 + m * 16 + lh * 4 + r] = rs[m][r];
        }
    __syncthreads();
    if (t < 128)
        partial[(size_t)(rb + t) * nCB + blockIdx.y] = red[0][t] + red[1][t];
}

// ---------------------------------------------------------------------------
// Finalize: one wave per row — gather target/cluster logits, assemble NLL.
// ---------------------------------------------------------------------------
__global__ void pals_finalize(const ushort* __restrict__ Hb,
                              const int* __restrict__ target,
                              const float* __restrict__ w0, const float* __restrict__ b0,
                              const float* __restrict__ w1, const float* __restrict__ b1,
                              const float* __restrict__ w2, const float* __restrict__ b2,
                              const float* __restrict__ w3, const float* __restrict__ b3,
                              const float* __restrict__ cw, const float* __restrict__ cbv,
                              const float* __restrict__ pH,
                              const float* __restrict__ pT1,
                              const float* __restrict__ pT2,
                              const float* __restrict__ pT3,
                              float* __restrict__ out) {
    const int wave = threadIdx.x >> 6;
    const int lane = threadIdx.x & 63;
    const int row  = blockIdx.x * 4 + wave;
    if (row >= NROW) return;
    const int t = target[row];
    const ushort* Hrow = Hb + (size_t)row * LDHB;

    float s = 0.f;
    for (int c = lane; c < NBH; c += 64) s += pH[(size_t)row * NBH + c];
    #pragma unroll
    for (int off = 32; off; off >>= 1) s += __shfl_xor(s, off);
    const float logSh = logf(s);

    float nll;
    if (t < 20000) {
        const float* wr0 = w0 + (size_t)t * 1024;
        float d = 0.f;
        for (int k = lane * 4; k < 1024; k += 256) {
            ushort4 a = *(const ushort4*)(Hrow + k);
            float4  b = *(const float4*)(wr0 + k);
            d += bf2f(a.x) * b.x + bf2f(a.y) * b.y + bf2f(a.z) * b.z + bf2f(a.w) * b.w;
        }
        #pragma unroll
        for (int off = 32; off; off >>= 1) d += __shfl_xor(d, off);
        nll = -(d + b0[t] - logSh);
    } else {
        const int i  = (t - 20000) / 10000 + 1;        // 1..3
        const int ci = 3 - i;                           // head_lp[:, -i] quirk
        const float* cwr = cw + (size_t)ci * 1024;
        float d = 0.f;
        for (int k = lane * 4; k < 1024; k += 256) {
            ushort4 a = *(const ushort4*)(Hrow + k);
            float4  b = *(const float4*)(cwr + k);
            d += bf2f(a.x) * b.x + bf2f(a.y) * b.y + bf2f(a.z) * b.z + bf2f(a.w) * b.w;
        }
        #pragma unroll
        for (int off = 32; off; off >>= 1) d += __shfl_xor(d, off);
        const float logit_c = d + cbv[ci];

        const int dl   = 1024 >> (2 * i);               // 256, 64, 16
        const int hoff = (i == 1) ? 1024 : (i == 2) ? 1280 : 1344;
        const float* wi = (i == 1) ? w1 : (i == 2) ? w2 : w3;
        const float* bi = (i == 1) ? b1 : (i == 2) ? b2 : b3;
        const float* pT = (i == 1) ? pT1 : (i == 2) ? pT2 : pT3;
        const int nbi  = (i == 1) ? NBT1 : NBT;
        const int tt = t - (20000 + (i - 1) * 10000);

        float dt = 0.f;
        const ushort* Hi = Hrow + hoff;
        for (int k = lane; k < dl; k += 64) dt += bf2f(Hi[k]) * wi[(size_t)tt * dl + k];
        #pragma unroll
        for (int off = 32; off; off >>= 1) dt += __shfl_xor(dt, off);

        float st = 0.f;
        for (int c = lane; c < nbi; c += 64) st += pT[(size_t)row * nbi + c];
        #pragma unroll
        for (int off = 32; off; off >>= 1) st += __shfl_xor(st, off);

        nll = -((logit_c - logSh) + (dt + bi[tt] - logf(st)));
    }
    if (lane == 0) out[row] = nll;
}

// ---------------------------------------------------------------------------
extern "C" void kernel_launch(void* const* d_in, const int* in_sizes, int n_in,
                              void* d_out, int out_size, void* d_ws, size_t ws_size,
                              hipStream_t stream) {
    const float* hidden = (const float*)d_in[0];
    const int*   target = (const int*)  d_in[1];
    const float* proj0  = (const float*)d_in[2];
    const float* w0     = (const float*)d_in[3];
    const float* b0     = (const float*)d_in[4];
    const float* proj1  = (const float*)d_in[5];
    const float* w1     = (const float*)d_in[6];
    const float* b1     = (const float*)d_in[7];
    const float* proj2  = (const float*)d_in[8];
    const float* w2     = (const float*)d_in[9];
    const float* b2     = (const float*)d_in[10];
    const float* proj3  = (const float*)d_in[11];
    const float* w3     = (const float*)d_in[12];
    const float* b3     = (const float*)d_in[13];
    const float* cw     = (const float*)d_in[14];
    const float* cbv    = (const float*)d_in[15];

    ushort* hb  = (ushort*)d_ws;                         // [4096][1024]
    ushort* pbT = hb  + (size_t)NROW * DPROJ;            // [1408][1024]
    ushort* Hb  = pbT + (size_t)LDHB * DPROJ;            // [4096][1408]
    ushort* WH  = Hb  + (size_t)NROW * LDHB;             // [20224][1024]
    ushort* WT1 = WH  + (size_t)HEAD_VP * 1024;          // [10240][256]
    ushort* WT2 = WT1 + (size_t)TAIL1_P * 256;           // [10112][64]
    ushort* WT3 = WT2 + (size_t)TAIL_VP * 64;            // [10112][32]
    float*  pH  = (float*)(WT3 + (size_t)TAIL_VP * 32);  // [4096][79]
    float*  pT1 = pH  + (size_t)NROW * NBH;              // [4096][40]
    float*  pT2 = pT1 + (size_t)NROW * NBT1;             // [4096][79]
    float*  pT3 = pT2 + (size_t)NROW * NBT;              // [4096][79]

    dim3 blk(256);
    cast_hidden_k<<<dim3(NROW * DPROJ / 1024), blk, 0, stream>>>(hidden, hb);
    cast_transpose_proj<<<dim3(16, 22), blk, 0, stream>>>(proj0, proj1, proj2, proj3, pbT);
    cast_head_w<<<dim3(HEAD_VP), blk, 0, stream>>>(w0, cw, WH);
    cast_tail_w<256><<<dim3(TAIL1_P), blk, 0, stream>>>(w1, WT1, TAIL_V, 256, TAIL1_P);
    cast_tail_w<64><<<dim3((TAIL_VP * 64 + 255) / 256), blk, 0, stream>>>(w2, WT2, TAIL_V, 64, TAIL_VP);
    cast_tail_w<32><<<dim3((TAIL_VP * 32 + 255) / 256), blk, 0, stream>>>(w3, WT3, TAIL_V, 16, TAIL_VP);

    proj_gemm_mfma<<<dim3(32, 11), blk, 0, stream>>>(hb, pbT, Hb);

    // head: 16 x 79 = 1264 blocks (1264 % 8 == 0), 96 KB dynamic LDS
    gemm_sumexp_256<1024><<<dim3(16 * NBH), dim3(512), 98304, stream>>>(
        Hb, LDHB, WH, b0, cbv, 20000, HEAD_V, pH, NBH, 16);
    // tail1: 16 x 40 = 640 blocks
    gemm_sumexp_256<256><<<dim3(16 * NBT1), dim3(512), 98304, stream>>>(
        Hb + 1024, LDHB, WT1, b1, b1, TAIL_V, TAIL_V, pT1, NBT1, 16);
    // tails 2,3 on the 128-tile kernel
    gemm_sumexp_bf<64><<<dim3(32, NBT), blk, 0, stream>>>(
        Hb + 1280, WT2, b2, TAIL_V, pT2, NBT);
    gemm_sumexp_bf<32><<<dim3(32, NBT), blk, 0, stream>>>(
        Hb + 1344, WT3, b3, TAIL_V, pT3, NBT);

    pals_finalize<<<dim3(NROW / 4), blk, 0, stream>>>(
        Hb, target, w0, b0, w1, b1, w2, b2, w3, b3, cw, cbv,
        pH, pT1, pT2, pT3, (float*)d_out);
}